// Round 4
// baseline (460.423 us; speedup 1.0000x reference)
//
#include <hip/hip_runtime.h>
#include <math.h>
#include <stdint.h>

#define NV 8192        // N (nodes)
#define KD 256         // IN_DIM
#define DD 64          // OUT_DIM
#define ALPHA 0.2f
#define TI 64          // rows per block tile
#define CJ 128         // j-chunk (16 chunks of 8 f16)
#define BLK 512

typedef _Float16 half8 __attribute__((ext_vector_type(8)));
typedef float floatx4 __attribute__((ext_vector_type(4)));

// ws layout (float offsets)
#define OFF_WHT  0                        // WhT f16 [DD][NV] = 262144 floats
#define OFF_F1   (DD * NV / 2)
#define OFF_F2   (OFF_F1 + NV)
#define OFF_PACC (OFF_F2 + NV)            // then pacc[S][NV][DD], pl[S][NV]

// ---------------- kernel 1: WhT(f16) = (h@W)^T, f1 = Wh@a1, f2 = Wh@a2 ----------------
// 16 rows/block, 4 rows/thread: W element reused x4 -> W L2 traffic 537->134 MB.
__global__ __launch_bounds__(256) void gat_pre(
    const float* __restrict__ h, const float* __restrict__ W,
    const float* __restrict__ a, ushort* __restrict__ whT,
    float* __restrict__ f1, float* __restrict__ f2) {
  __shared__ float hrow[16][KD];            // 16 KB
  __shared__ ushort tw[DD][20];             // transpose staging (+4 pad)
  const int tid = threadIdx.x;
  const int i0 = blockIdx.x * 16;
#pragma unroll
  for (int u = 0; u < 4; ++u) {
    const int idx = tid + u * 256;          // 1024 float4 slots = 16 rows x 64
    const int row = idx >> 6, col = (idx & 63) * 4;
    *(float4*)&hrow[row][col] = *(const float4*)&h[(long long)(i0 + row) * KD + col];
  }
  __syncthreads();
  const int d = tid & 63;                   // output col
  const int rg = tid >> 6;                  // wave -> 4 rows rg*4..rg*4+3
  float wh[4] = {0.f, 0.f, 0.f, 0.f};
#pragma unroll 4
  for (int c = 0; c < KD; ++c) {
    const float wc = W[c * DD + d];
#pragma unroll
    for (int r = 0; r < 4; ++r) wh[r] += hrow[rg * 4 + r][c] * wc;
  }
  const float a1 = a[d], a2 = a[DD + d];
#pragma unroll
  for (int r = 0; r < 4; ++r) {
    float p1 = wh[r] * a1, p2 = wh[r] * a2;
#pragma unroll
    for (int off = 32; off > 0; off >>= 1) {
      p1 += __shfl_down(p1, off);
      p2 += __shfl_down(p2, off);
    }
    if (d == 0) { f1[i0 + rg * 4 + r] = p1; f2[i0 + rg * 4 + r] = p2; }
    union { _Float16 hf; ushort u; } cv;
    cv.hf = (_Float16)wh[r];
    tw[d][rg * 4 + r] = cv.u;
  }
  __syncthreads();
  if (tid < 128) {                          // row d, 16 f16 = two 16B stores
    const int dd = tid >> 1, hf = tid & 1;
    *(uint4*)&whT[(long long)dd * NV + i0 + hf * 8] = *(uint4*)&tw[dd][hf * 8];
  }
}

// ---------------- kernel 2: fused masked-softmax attention @ Wh (MFMA f16) ----------------
// Software-pipelined: next chunk's A/whT/f2 prefetched into registers before the
// barrier so HBM latency rides under current chunk's stage-1 + MFMA.
__global__ __launch_bounds__(BLK) void gat_main(
    const int* __restrict__ A, const ushort* __restrict__ whT,
    const float* __restrict__ f1, const float* __restrict__ f2,
    float* __restrict__ pacc, float* __restrict__ pl, int S) {
  __shared__ __align__(16) ushort w_lds[TI * CJ];  // 16 KB, A-operand (rows i)
  __shared__ __align__(16) ushort b_lds[TI * CJ];  // 16 KB, B-operand (rows d)
  __shared__ float f1_lds[TI], M_lds[TI], redf[8];

  const int tid = threadIdx.x;
  const int wave = tid >> 6, lane = tid & 63;
  const int tile = blockIdx.x & 127;  // NV/TI = 128
  const int s = blockIdx.x >> 7;
  const int i0 = tile * TI;
  const int jrange = NV / S;
  const int j0 = s * jrange;

  // block-redundant global max of f2 (f2 is L2-resident, 32 KB)
  float m = -1e30f;
#pragma unroll
  for (int q = 0; q < 16; ++q) m = fmaxf(m, f2[tid + q * BLK]);
#pragma unroll
  for (int off = 32; off > 0; off >>= 1) m = fmaxf(m, __shfl_down(m, off));
  if (lane == 0) redf[wave] = m;
  __syncthreads();
  if (tid < TI) {
    float mm = redf[0];
#pragma unroll
    for (int k = 1; k < 8; ++k) mm = fmaxf(mm, redf[k]);
    float v = f1[i0 + tid];
    f1_lds[tid] = v;
    float x = v + mm;                      // M_i = lrelu(f1_i + max f2) >= row max
    M_lds[tid] = x > 0.f ? x : ALPHA * x;  // (lrelu monotone) -> w <= 1, f16-safe
  }

  // stage-1 mapping: thread covers cols c4..c4+3 of rows rb+16p
  const int c4 = (tid & 31) * 4;
  const int k8w = (tid & 31) >> 1;   // 16B-chunk col for writes
  const int sub = (tid & 1) * 8;     // byte offset within chunk
  const int rb = tid >> 5;           // 0..15
  // b-gather mapping
  const int bn0 = tid >> 4, bc0 = tid & 15;             // u=0
  const int bn1 = (tid + BLK) >> 4, bc1 = tid & 15;     // u=1 (c repeats every 16)
  // MFMA mapping: wave -> m-tile (wave>>1), two n-tiles
  const int mt = wave >> 1;
  const int nt0 = (wave & 1) * 2;
  const int m_ = lane & 15, quad = lane >> 4;

  floatx4 acc0 = {0.f, 0.f, 0.f, 0.f}, acc1 = {0.f, 0.f, 0.f, 0.f};
  float lp[4] = {0.f, 0.f, 0.f, 0.f};

  int4 a_cur[4], a_nxt[4];
  uint4 b_cur[2], b_nxt[2];
  float4 f2_cur, f2_nxt;

  // preload chunk 0
  {
    const int jb = j0;
#pragma unroll
    for (int p = 0; p < 4; ++p)
      a_cur[p] = *(const int4*)(A + (long long)(i0 + rb + 16 * p) * NV + jb + c4);
    b_cur[0] = *(const uint4*)(whT + (long long)bn0 * NV + jb + 8 * (bc0 ^ (bn0 & 15)));
    b_cur[1] = *(const uint4*)(whT + (long long)bn1 * NV + jb + 8 * (bc1 ^ (bn1 & 15)));
    f2_cur = *(const float4*)(f2 + jb + c4);
  }

  const int nch = jrange / CJ;
  for (int ch = 0; ch < nch; ++ch) {
    // ---- issue next chunk's global loads (in flight through stage-1 + MFMA) ----
    if (ch + 1 < nch) {
      const int jb = j0 + (ch + 1) * CJ;
#pragma unroll
      for (int p = 0; p < 4; ++p)
        a_nxt[p] = *(const int4*)(A + (long long)(i0 + rb + 16 * p) * NV + jb + c4);
      b_nxt[0] = *(const uint4*)(whT + (long long)bn0 * NV + jb + 8 * (bc0 ^ (bn0 & 15)));
      b_nxt[1] = *(const uint4*)(whT + (long long)bn1 * NV + jb + 8 * (bc1 ^ (bn1 & 15)));
      f2_nxt = *(const float4*)(f2 + jb + c4);
    }
    __syncthreads();  // previous chunk's LDS readers done (also covers M_lds init)

    // ---- stage B chunk from registers into LDS (XOR-swizzled slots) ----
    *(uint4*)&b_lds[(tid) * 8] = b_cur[0];
    *(uint4*)&b_lds[(tid + BLK) * 8] = b_cur[1];

    // ---- stage 1: w = A ? exp(lrelu(f1+f2) - M) : 0, as f16 into w_lds ----
#pragma unroll
    for (int p = 0; p < 4; ++p) {
      const int r = rb + 16 * p;
      const int4 a4 = a_cur[p];
      const float f1r = f1_lds[r], Mr = M_lds[r];
      float w0, w1, w2, w3;
      { float x = f1r + f2_cur.x; x = x > 0.f ? x : ALPHA * x; w0 = (a4.x > 0) ? __expf(x - Mr) : 0.f; }
      { float x = f1r + f2_cur.y; x = x > 0.f ? x : ALPHA * x; w1 = (a4.y > 0) ? __expf(x - Mr) : 0.f; }
      { float x = f1r + f2_cur.z; x = x > 0.f ? x : ALPHA * x; w2 = (a4.z > 0) ? __expf(x - Mr) : 0.f; }
      { float x = f1r + f2_cur.w; x = x > 0.f ? x : ALPHA * x; w3 = (a4.w > 0) ? __expf(x - Mr) : 0.f; }
      union { _Float16 hf[4]; uint2 u2; } pk;
      pk.hf[0] = (_Float16)w0; pk.hf[1] = (_Float16)w1;
      pk.hf[2] = (_Float16)w2; pk.hf[3] = (_Float16)w3;
      // sum the f16-rounded values so softmax stays exactly normalized
      lp[p] += (float)pk.hf[0] + (float)pk.hf[1] + (float)pk.hf[2] + (float)pk.hf[3];
      *(uint2*)((char*)w_lds + (r * 16 + (k8w ^ (r & 15))) * 16 + sub) = pk.u2;
    }
    __syncthreads();

    // ---- stage 2: MFMA, 2 C-tiles per wave, 4 k-steps ----
#pragma unroll
    for (int ks = 0; ks < 4; ++ks) {
      const int cc = 4 * ks + quad;
      const half8 af = *(const half8*)((const char*)w_lds + (((16 * mt + m_) * 16) + (cc ^ m_)) * 16);
      const half8 b0 = *(const half8*)((const char*)b_lds + (((16 * nt0 + m_) * 16) + (cc ^ m_)) * 16);
      const half8 b1 = *(const half8*)((const char*)b_lds + (((16 * (nt0 + 1) + m_) * 16) + (cc ^ m_)) * 16);
      acc0 = __builtin_amdgcn_mfma_f32_16x16x32_f16(af, b0, acc0, 0, 0, 0);
      acc1 = __builtin_amdgcn_mfma_f32_16x16x32_f16(af, b1, acc1, 0, 0, 0);
    }

    // rotate pipeline registers
#pragma unroll
    for (int p = 0; p < 4; ++p) a_cur[p] = a_nxt[p];
    b_cur[0] = b_nxt[0]; b_cur[1] = b_nxt[1];
    f2_cur = f2_nxt;
  }

  // ---- pl: reduce thread-local row-sum partials across each 32-lane group ----
#pragma unroll
  for (int p = 0; p < 4; ++p) {
    float v = lp[p];
    v += __shfl_down(v, 16, 32);
    v += __shfl_down(v, 8, 32);
    v += __shfl_down(v, 4, 32);
    v += __shfl_down(v, 2, 32);
    v += __shfl_down(v, 1, 32);
    if ((tid & 31) == 0) pl[(long long)s * NV + i0 + rb + 16 * p] = v;
  }

  // ---- epilogue: C/D layout row=quad*4+reg, col=lane&15 (verified m89/m91) ----
#pragma unroll
  for (int reg = 0; reg < 4; ++reg) {
    const int i = i0 + 16 * mt + quad * 4 + reg;
    const long long base = ((long long)s * NV + i) * DD + m_;
    pacc[base + 16 * nt0] = acc0[reg];
    pacc[base + 16 * (nt0 + 1)] = acc1[reg];
  }
}

// ---------------- kernel 3: combine j-splits, normalize, ELU ----------------
__global__ __launch_bounds__(256) void gat_fin(const float* __restrict__ pacc,
                                               const float* __restrict__ pl,
                                               float* __restrict__ out, int S) {
  const int idx = blockIdx.x * 256 + threadIdx.x;
  const int i = idx >> 6;
  float sum = 0.f, l = 0.f;
  for (int q = 0; q < S; ++q) sum += pacc[(long long)q * (NV * DD) + idx];
  for (int q = 0; q < S; ++q) l += pl[q * NV + i];
  const float v = sum / l;
  out[idx] = v > 0.f ? v : expm1f(v);  // ELU, alpha=1
}

extern "C" void kernel_launch(void* const* d_in, const int* in_sizes, int n_in,
                              void* d_out, int out_size, void* d_ws, size_t ws_size,
                              hipStream_t stream) {
  const float* h = (const float*)d_in[0];
  const int* A = (const int*)d_in[1];
  const float* W = (const float*)d_in[2];
  const float* a = (const float*)d_in[3];
  float* out = (float*)d_out;
  float* ws = (float*)d_ws;

  ushort* whT = (ushort*)(ws + OFF_WHT);
  float* f1 = ws + OFF_F1;
  float* f2 = ws + OFF_F2;
  float* pacc = ws + OFF_PACC;

  // pick largest j-split S that fits the workspace
  int S = 8;
  while (S > 1 &&
         (size_t)(OFF_PACC + (size_t)S * (NV * DD + NV)) * sizeof(float) > ws_size)
    S >>= 1;
  float* pl = pacc + (size_t)S * NV * DD;

  gat_pre<<<NV / 16, 256, 0, stream>>>(h, W, a, whT, f1, f2);
  gat_main<<<(NV / TI) * S, BLK, 0, stream>>>(A, whT, f1, f2, pacc, pl, S);
  gat_fin<<<NV * DD / 256, 256, 0, stream>>>(pacc, pl, out, S);
}

// Round 5
// 456.902 us; speedup vs baseline: 1.0077x; 1.0077x over previous
//
#include <hip/hip_runtime.h>
#include <math.h>
#include <stdint.h>

#define NV 8192        // N (nodes)
#define KD 256         // IN_DIM
#define DD 64          // OUT_DIM
#define ALPHA 0.2f
#define TI 64          // rows per block tile (4 waves x 16-row m-tiles)
#define SPLIT 8        // j-splits
#define BLK 256

typedef _Float16 half8 __attribute__((ext_vector_type(8)));
typedef float floatx4 __attribute__((ext_vector_type(4)));

// ws layout (float offsets)
#define OFF_WHT  0                        // WhT f16 [DD][NV] = 262144 floats
#define OFF_F1   (DD * NV / 2)
#define OFF_F2   (OFF_F1 + NV)
#define OFF_PACC (OFF_F2 + NV)            // then pacc[S][NV][DD], pl[S][NV]

// ---------------- kernel 1: WhT(f16) = (h@W)^T, f1 = Wh@a1, f2 = Wh@a2 ----------------
// 16 rows/block, 4 rows/thread: W element reused x4 (unchanged from R4 - passed).
__global__ __launch_bounds__(256) void gat_pre(
    const float* __restrict__ h, const float* __restrict__ W,
    const float* __restrict__ a, ushort* __restrict__ whT,
    float* __restrict__ f1, float* __restrict__ f2) {
  __shared__ float hrow[16][KD];            // 16 KB
  __shared__ ushort tw[DD][20];             // transpose staging (+4 pad)
  const int tid = threadIdx.x;
  const int i0 = blockIdx.x * 16;
#pragma unroll
  for (int u = 0; u < 4; ++u) {
    const int idx = tid + u * 256;          // 1024 float4 slots = 16 rows x 64
    const int row = idx >> 6, col = (idx & 63) * 4;
    *(float4*)&hrow[row][col] = *(const float4*)&h[(long long)(i0 + row) * KD + col];
  }
  __syncthreads();
  const int d = tid & 63;                   // output col
  const int rg = tid >> 6;                  // wave -> 4 rows rg*4..rg*4+3
  float wh[4] = {0.f, 0.f, 0.f, 0.f};
#pragma unroll 4
  for (int c = 0; c < KD; ++c) {
    const float wc = W[c * DD + d];
#pragma unroll
    for (int r = 0; r < 4; ++r) wh[r] += hrow[rg * 4 + r][c] * wc;
  }
  const float a1 = a[d], a2 = a[DD + d];
#pragma unroll
  for (int r = 0; r < 4; ++r) {
    float p1 = wh[r] * a1, p2 = wh[r] * a2;
#pragma unroll
    for (int off = 32; off > 0; off >>= 1) {
      p1 += __shfl_down(p1, off);
      p2 += __shfl_down(p2, off);
    }
    if (d == 0) { f1[i0 + rg * 4 + r] = p1; f2[i0 + rg * 4 + r] = p2; }
    union { _Float16 hf; ushort u; } cv;
    cv.hf = (_Float16)wh[r];
    tw[d][rg * 4 + r] = cv.u;
  }
  __syncthreads();
  if (tid < 128) {                          // row d, 16 f16
    const int dd = tid >> 1, hf = tid & 1;
    *(uint4*)&whT[(long long)dd * NV + i0 + hf * 8] = *(uint4*)&tw[dd][hf * 8];
  }
}

// ---------------- kernel 2: fused masked-softmax attention @ Wh (MFMA f16) ----------------
// Barrier-free K-loop: both MFMA operands built directly in registers.
//  A-frag (w):  lane(m_,quad) computes w[row=i0+16*wave+m_][kb+quad*8+0..7]
//               from two int4 A loads + f2 (LDS, staged once) + f1r/Mr consts.
//  B-frag:      16B global load whT[n=16*nt+m_][kb+quad*8+0..7]  (L2-resident, 1 MB).
// K-window identical to R3/R4's verified LDS path (32*ks+quad*8) -> mapping proven.
// amdgpu_waves_per_eu(4,8): pins VGPR budget to 128 so the compiler cannot repeat
// the R1/R2/R4 spill (it defaults to an 8-wave/64-VGPR target when LDS is small).
__global__ __launch_bounds__(BLK) __attribute__((amdgpu_waves_per_eu(4, 8)))
void gat_main(
    const int* __restrict__ A, const ushort* __restrict__ whT,
    const float* __restrict__ f1, const float* __restrict__ f2,
    float* __restrict__ pacc, float* __restrict__ pl, int S) {
  __shared__ float f2_lds[NV / SPLIT];   // 4 KB at S=8
  __shared__ float redf[4];

  const int tid = threadIdx.x;
  const int wave = tid >> 6, lane = tid & 63;
  const int m_ = lane & 15, quad = lane >> 4;
  const int tile = blockIdx.x & 127;     // NV/TI = 128
  const int s = blockIdx.x >> 7;
  const int i0 = tile * TI;
  const int jrange = NV / S;
  const int j0 = s * jrange;

  // block-redundant global max of f2 (f2 is 32 KB, L2-resident)
  float m = -1e30f;
#pragma unroll
  for (int q = 0; q < NV / BLK; ++q) m = fmaxf(m, f2[tid + q * BLK]);
#pragma unroll
  for (int off = 32; off > 0; off >>= 1) m = fmaxf(m, __shfl_down(m, off));
  if (lane == 0) redf[wave] = m;

  // stage this block's f2 window (only LDS the K-loop touches)
  for (int u = tid * 4; u < jrange; u += BLK * 4)
    *(float4*)&f2_lds[u] = *(const float4*)&f2[j0 + u];
  __syncthreads();

  const float mm = fmaxf(fmaxf(redf[0], redf[1]), fmaxf(redf[2], redf[3]));
  const int row = i0 + wave * 16 + m_;
  const float f1r = f1[row];
  const float xm = f1r + mm;                 // M = lrelu(f1 + max f2) >= row max
  const float Mr = fmaxf(xm, ALPHA * xm);    // (lrelu monotone) -> w <= 1, f16-safe

  floatx4 acc[4];
#pragma unroll
  for (int nt = 0; nt < 4; ++nt) acc[nt] = (floatx4){0.f, 0.f, 0.f, 0.f};
  float lp = 0.f;

  const int* Arow = A + (long long)row * NV + j0 + quad * 8;
  const ushort* Bb = whT + j0 + quad * 8;

  int4 aC0 = *(const int4*)(Arow);
  int4 aC1 = *(const int4*)(Arow + 4);
  half8 bC[4];
#pragma unroll
  for (int nt = 0; nt < 4; ++nt)
    bC[nt] = *(const half8*)(Bb + (long long)(nt * 16 + m_) * NV);

  for (int kb = 0; kb < jrange; kb += 32) {
    // prefetch next k-window (rides under this window's VALU + MFMA)
    const int nxt = (kb + 32 < jrange) ? kb + 32 : 0;
    int4 aN0 = *(const int4*)(Arow + nxt);
    int4 aN1 = *(const int4*)(Arow + nxt + 4);
    half8 bN[4];
#pragma unroll
    for (int nt = 0; nt < 4; ++nt)
      bN[nt] = *(const half8*)(Bb + (long long)(nt * 16 + m_) * NV + nxt);

    const int kk = kb + quad * 8;
    const float4 q0 = *(const float4*)&f2_lds[kk];
    const float4 q1 = *(const float4*)&f2_lds[kk + 4];

    union { _Float16 hf[8]; half8 v; } wf;
#define WELT(slot, aval, f2val)                                        \
    { float x = f1r + (f2val); x = fmaxf(x, ALPHA * x);                \
      float w = ((aval) > 0) ? __expf(x - Mr) : 0.f;                   \
      wf.hf[slot] = (_Float16)w; lp += (float)wf.hf[slot]; }
    WELT(0, aC0.x, q0.x) WELT(1, aC0.y, q0.y)
    WELT(2, aC0.z, q0.z) WELT(3, aC0.w, q0.w)
    WELT(4, aC1.x, q1.x) WELT(5, aC1.y, q1.y)
    WELT(6, aC1.z, q1.z) WELT(7, aC1.w, q1.w)
#undef WELT

    acc[0] = __builtin_amdgcn_mfma_f32_16x16x32_f16(wf.v, bC[0], acc[0], 0, 0, 0);
    acc[1] = __builtin_amdgcn_mfma_f32_16x16x32_f16(wf.v, bC[1], acc[1], 0, 0, 0);
    acc[2] = __builtin_amdgcn_mfma_f32_16x16x32_f16(wf.v, bC[2], acc[2], 0, 0, 0);
    acc[3] = __builtin_amdgcn_mfma_f32_16x16x32_f16(wf.v, bC[3], acc[3], 0, 0, 0);

    aC0 = aN0; aC1 = aN1;
#pragma unroll
    for (int nt = 0; nt < 4; ++nt) bC[nt] = bN[nt];
  }

  // ---- pl: row sums. lp's row is m_; quads sit at lane, lane+16, +32, +48 ----
  {
    float v = lp;
    v += __shfl_down(v, 32);
    v += __shfl_down(v, 16);
    if (lane < 16) pl[(long long)s * NV + row] = v;  // row = i0+16*wave+m_ (lane<16 => quad==0)
  }

  // ---- epilogue: C/D layout row=quad*4+reg, col=lane&15 (verified m89/m91) ----
#pragma unroll
  for (int reg = 0; reg < 4; ++reg) {
    const int i = i0 + wave * 16 + quad * 4 + reg;
    const long long base = ((long long)s * NV + i) * DD + m_;
#pragma unroll
    for (int nt = 0; nt < 4; ++nt) pacc[base + 16 * nt] = acc[nt][reg];
  }
}

// ---------------- kernel 3: combine j-splits, normalize, ELU ----------------
__global__ __launch_bounds__(256) void gat_fin(const float* __restrict__ pacc,
                                               const float* __restrict__ pl,
                                               float* __restrict__ out, int S) {
  const int idx = blockIdx.x * 256 + threadIdx.x;
  const int i = idx >> 6;
  float sum = 0.f, l = 0.f;
  for (int q = 0; q < S; ++q) sum += pacc[(long long)q * (NV * DD) + idx];
  for (int q = 0; q < S; ++q) l += pl[q * NV + i];
  const float v = sum / l;
  out[idx] = v > 0.f ? v : expm1f(v);  // ELU, alpha=1
}

extern "C" void kernel_launch(void* const* d_in, const int* in_sizes, int n_in,
                              void* d_out, int out_size, void* d_ws, size_t ws_size,
                              hipStream_t stream) {
  const float* h = (const float*)d_in[0];
  const int* A = (const int*)d_in[1];
  const float* W = (const float*)d_in[2];
  const float* a = (const float*)d_in[3];
  float* out = (float*)d_out;
  float* ws = (float*)d_ws;

  ushort* whT = (ushort*)(ws + OFF_WHT);
  float* f1 = ws + OFF_F1;
  float* f2 = ws + OFF_F2;
  float* pacc = ws + OFF_PACC;

  const int S = SPLIT;  // pacc+pl at S=8: ~19 MB, well under ws_size
  float* pl = pacc + (size_t)S * NV * DD;

  gat_pre<<<NV / 16, 256, 0, stream>>>(h, W, a, whT, f1, f2);
  gat_main<<<(NV / TI) * S, BLK, 0, stream>>>(A, whT, f1, f2, pacc, pl, S);
  gat_fin<<<NV * DD / 256, 256, 0, stream>>>(pacc, pl, out, S);
}

// Round 6
// 450.318 us; speedup vs baseline: 1.0224x; 1.0146x over previous
//
#include <hip/hip_runtime.h>
#include <math.h>
#include <stdint.h>

#define NV 8192        // N (nodes)
#define KD 256         // IN_DIM
#define DD 64          // OUT_DIM
#define ALPHA 0.2f
#define TI 64          // rows per block tile (4 waves x 16-row m-tiles)
#define SPLIT 16       // j-splits -> 2048 blocks -> 8 blocks/CU -> full occupancy
#define BLK 256

typedef _Float16 half8 __attribute__((ext_vector_type(8)));
typedef float floatx4 __attribute__((ext_vector_type(4)));

// ws layout (float offsets)
#define OFF_WHT  0                        // WhT f16 [DD][NV] = 262144 floats
#define OFF_F1   (DD * NV / 2)
#define OFF_F2   (OFF_F1 + NV)
#define OFF_PACC (OFF_F2 + NV)            // then pacc[S][NV][DD], pl[S][NV]

// ---------------- kernel 1: WhT(f16) = (h@W)^T, f1 = Wh@a1, f2 = Wh@a2 ----------------
__global__ __launch_bounds__(256) void gat_pre(
    const float* __restrict__ h, const float* __restrict__ W,
    const float* __restrict__ a, ushort* __restrict__ whT,
    float* __restrict__ f1, float* __restrict__ f2) {
  __shared__ float hrow[16][KD];            // 16 KB
  __shared__ ushort tw[DD][20];             // transpose staging (+4 pad)
  const int tid = threadIdx.x;
  const int i0 = blockIdx.x * 16;
#pragma unroll
  for (int u = 0; u < 4; ++u) {
    const int idx = tid + u * 256;          // 1024 float4 slots = 16 rows x 64
    const int row = idx >> 6, col = (idx & 63) * 4;
    *(float4*)&hrow[row][col] = *(const float4*)&h[(long long)(i0 + row) * KD + col];
  }
  __syncthreads();
  const int d = tid & 63;                   // output col
  const int rg = tid >> 6;                  // wave -> 4 rows rg*4..rg*4+3
  float wh[4] = {0.f, 0.f, 0.f, 0.f};
#pragma unroll 4
  for (int c = 0; c < KD; ++c) {
    const float wc = W[c * DD + d];
#pragma unroll
    for (int r = 0; r < 4; ++r) wh[r] += hrow[rg * 4 + r][c] * wc;
  }
  const float a1 = a[d], a2 = a[DD + d];
#pragma unroll
  for (int r = 0; r < 4; ++r) {
    float p1 = wh[r] * a1, p2 = wh[r] * a2;
#pragma unroll
    for (int off = 32; off > 0; off >>= 1) {
      p1 += __shfl_down(p1, off);
      p2 += __shfl_down(p2, off);
    }
    if (d == 0) { f1[i0 + rg * 4 + r] = p1; f2[i0 + rg * 4 + r] = p2; }
    union { _Float16 hf; ushort u; } cv;
    cv.hf = (_Float16)wh[r];
    tw[d][rg * 4 + r] = cv.u;
  }
  __syncthreads();
  if (tid < 128) {                          // row d, 16 f16
    const int dd = tid >> 1, hf = tid & 1;
    *(uint4*)&whT[(long long)dd * NV + i0 + hf * 8] = *(uint4*)&tw[dd][hf * 8];
  }
}

// ---------------- kernel 2: fused masked-softmax attention @ Wh (MFMA f16) ----------------
// Barrier-free K-loop, operands built in registers (R5 structure, verified).
// R6 changes: S=16 for 8 blocks/CU (latency hiding via occupancy - R5 was 40% occ,
// latency-bound); no explicit prefetch regs (compiler sinks them anyway, R5 VGPR=44
// proved it); row-sums via 5th MFMA with B=ones (C col n = rowsum for every n,
// C-row = i-row per verified layout) instead of 16 cvt+add VALU per iter.
__global__ __launch_bounds__(BLK) __attribute__((amdgpu_waves_per_eu(4, 8)))
void gat_main(
    const int* __restrict__ A, const ushort* __restrict__ whT,
    const float* __restrict__ f1, const float* __restrict__ f2,
    float* __restrict__ pacc, float* __restrict__ pl, int S) {
  __shared__ float f2_lds[NV / SPLIT];   // 2 KB at S=16
  __shared__ float redf[4];

  const int tid = threadIdx.x;
  const int wave = tid >> 6, lane = tid & 63;
  const int m_ = lane & 15, quad = lane >> 4;
  const int tile = blockIdx.x & 127;     // NV/TI = 128
  const int s = blockIdx.x >> 7;
  const int i0 = tile * TI;
  const int jrange = NV / S;
  const int j0 = s * jrange;

  // block-redundant global max of f2 (f2 is 32 KB, L2-resident)
  float m = -1e30f;
#pragma unroll
  for (int q = 0; q < NV / BLK; ++q) m = fmaxf(m, f2[tid + q * BLK]);
#pragma unroll
  for (int off = 32; off > 0; off >>= 1) m = fmaxf(m, __shfl_down(m, off));
  if (lane == 0) redf[wave] = m;

  // stage this block's f2 window (only LDS the K-loop touches)
  for (int u = tid * 4; u < jrange; u += BLK * 4)
    *(float4*)&f2_lds[u] = *(const float4*)&f2[j0 + u];
  __syncthreads();

  const float mm = fmaxf(fmaxf(redf[0], redf[1]), fmaxf(redf[2], redf[3]));
  const int row = i0 + wave * 16 + m_;
  const float f1r = f1[row];
  const float xm = f1r + mm;                 // M = lrelu(f1 + max f2) >= row max
  const float Mr = fmaxf(xm, ALPHA * xm);    // (lrelu monotone) -> w <= 1, f16-safe

  floatx4 acc[4], accl;
#pragma unroll
  for (int nt = 0; nt < 4; ++nt) acc[nt] = (floatx4){0.f, 0.f, 0.f, 0.f};
  accl = (floatx4){0.f, 0.f, 0.f, 0.f};
  const half8 ones = {(_Float16)1.f, (_Float16)1.f, (_Float16)1.f, (_Float16)1.f,
                      (_Float16)1.f, (_Float16)1.f, (_Float16)1.f, (_Float16)1.f};

  const int* Arow = A + (long long)row * NV + j0 + quad * 8;
  const ushort* Bb = whT + j0 + quad * 8;

  for (int kb = 0; kb < jrange; kb += 32) {
    const int4 a0 = *(const int4*)(Arow + kb);
    const int4 a1 = *(const int4*)(Arow + kb + 4);
    half8 b0 = *(const half8*)(Bb + (long long)(0 * 16 + m_) * NV + kb);
    half8 b1 = *(const half8*)(Bb + (long long)(1 * 16 + m_) * NV + kb);
    half8 b2 = *(const half8*)(Bb + (long long)(2 * 16 + m_) * NV + kb);
    half8 b3 = *(const half8*)(Bb + (long long)(3 * 16 + m_) * NV + kb);

    const int kk = kb + quad * 8;
    const float4 q0 = *(const float4*)&f2_lds[kk];
    const float4 q1 = *(const float4*)&f2_lds[kk + 4];

    union { _Float16 hf[8]; half8 v; } wf;
#define WELT(slot, aval, f2val)                                        \
    { float x = f1r + (f2val); x = fmaxf(x, ALPHA * x);                \
      float w = ((aval) > 0) ? __expf(x - Mr) : 0.f;                   \
      wf.hf[slot] = (_Float16)w; }
    WELT(0, a0.x, q0.x) WELT(1, a0.y, q0.y)
    WELT(2, a0.z, q0.z) WELT(3, a0.w, q0.w)
    WELT(4, a1.x, q1.x) WELT(5, a1.y, q1.y)
    WELT(6, a1.z, q1.z) WELT(7, a1.w, q1.w)
#undef WELT

    acc[0] = __builtin_amdgcn_mfma_f32_16x16x32_f16(wf.v, b0, acc[0], 0, 0, 0);
    acc[1] = __builtin_amdgcn_mfma_f32_16x16x32_f16(wf.v, b1, acc[1], 0, 0, 0);
    acc[2] = __builtin_amdgcn_mfma_f32_16x16x32_f16(wf.v, b2, acc[2], 0, 0, 0);
    acc[3] = __builtin_amdgcn_mfma_f32_16x16x32_f16(wf.v, b3, acc[3], 0, 0, 0);
    accl   = __builtin_amdgcn_mfma_f32_16x16x32_f16(wf.v, ones, accl, 0, 0, 0);
  }

  // ---- pl from ones-MFMA: lane(m_, quad) reg r holds rowsum of i-row quad*4+r;
  //      identical across m_, so only m_==0 writes ----
  if (m_ == 0) {
#pragma unroll
    for (int reg = 0; reg < 4; ++reg)
      pl[(long long)s * NV + i0 + wave * 16 + quad * 4 + reg] = accl[reg];
  }

  // ---- epilogue: C/D layout row=quad*4+reg, col=lane&15 (verified m89/m91) ----
#pragma unroll
  for (int reg = 0; reg < 4; ++reg) {
    const int i = i0 + wave * 16 + quad * 4 + reg;
    const long long base = ((long long)s * NV + i) * DD + m_;
#pragma unroll
    for (int nt = 0; nt < 4; ++nt) pacc[base + 16 * nt] = acc[nt][reg];
  }
}

// ---------------- kernel 3: combine j-splits, normalize, ELU ----------------
__global__ __launch_bounds__(256) void gat_fin(const float* __restrict__ pacc,
                                               const float* __restrict__ pl,
                                               float* __restrict__ out, int S) {
  const int idx = blockIdx.x * 256 + threadIdx.x;
  const int i = idx >> 6;
  float sum = 0.f, l = 0.f;
  for (int q = 0; q < S; ++q) sum += pacc[(long long)q * (NV * DD) + idx];
  for (int q = 0; q < S; ++q) l += pl[q * NV + i];
  const float v = sum / l;
  out[idx] = v > 0.f ? v : expm1f(v);  // ELU, alpha=1
}

extern "C" void kernel_launch(void* const* d_in, const int* in_sizes, int n_in,
                              void* d_out, int out_size, void* d_ws, size_t ws_size,
                              hipStream_t stream) {
  const float* h = (const float*)d_in[0];
  const int* A = (const int*)d_in[1];
  const float* W = (const float*)d_in[2];
  const float* a = (const float*)d_in[3];
  float* out = (float*)d_out;
  float* ws = (float*)d_ws;

  ushort* whT = (ushort*)(ws + OFF_WHT);
  float* f1 = ws + OFF_F1;
  float* f2 = ws + OFF_F2;
  float* pacc = ws + OFF_PACC;

  const int S = SPLIT;  // pacc+pl at S=16: ~34 MB, well under ws_size (~1 GB)
  float* pl = pacc + (size_t)S * NV * DD;

  gat_pre<<<NV / 16, 256, 0, stream>>>(h, W, a, whT, f1, f2);
  gat_main<<<(NV / TI) * S, BLK, 0, stream>>>(A, whT, f1, f2, pacc, pl, S);
  gat_fin<<<NV * DD / 256, 256, 0, stream>>>(pacc, pl, out, S);
}